// Round 1
// 1253.574 us; speedup vs baseline: 1.6455x; 1.6455x over previous
//
#include <hip/hip_runtime.h>

#define N_NODES 50000
#define N_EDGES 800000
#define N_ELEM  10
#define F_IN    128
#define F_OUT   128
#define NQ      100            // N_ELEM * N_ELEM
#define C_STRIDE 104           // c row stride (fits in the 128-f M row region)
#define EPW      8             // edges per wave
#define NGROUPS (N_EDGES / EPW)   // 100000 exactly
#define NWAVES  10
#define BLOCK   (NWAVES * 64)

// LDS layout (floats):
//   Wd  [100][128]      offset 0       (12800 f)  diag(weights1)
//   W2s [128][128]      offset 12800   (16384 f)
//   buf [NWAVES][1024]  offset 29184   per-wave union: c[8][104] overlaid by M[8][128]
// total = 29184 + 10*1024 = 39424 floats = 157696 B  (< 160 KiB)
#define SMEM_FLOATS (29184 + NWAVES * 1024)

#define FMA4(acc, s, v)                      \
    acc.x = fmaf((s), (v).x, acc.x);         \
    acc.y = fmaf((s), (v).y, acc.y);         \
    acc.z = fmaf((s), (v).z, acc.z);         \
    acc.w = fmaf((s), (v).w, acc.w);

__global__ __launch_bounds__(BLOCK, 1)
void tpwb_kernel(const float* __restrict__ na,
                 const float* __restrict__ ef,
                 const void*  __restrict__ eidx,
                 const float* __restrict__ w1,
                 const float* __restrict__ w2,
                 float* __restrict__ outp)
{
    extern __shared__ float smem[];
    float* Wd  = smem;            // [100][128]
    float* W2s = smem + 12800;    // [128][128]
    const int tid  = threadIdx.x;
    const int lane = tid & 63;
    const int w    = tid >> 6;
    float* bw = smem + 29184 + w * 1024;   // per-wave c/M union

    // ---- detect edge_index dtype: int64 -> all odd dwords of first 16 entries are 0
    const int* p32 = (const int*)eidx;
    bool is64 = true;
    #pragma unroll
    for (int k = 1; k < 32; k += 2) { if (p32[k] != 0) is64 = false; }
    const long long* p64 = (const long long*)eidx;

    // ---- stage weights into LDS (once per persistent block)
    for (int i = tid; i < NQ * F_IN; i += BLOCK) {
        int q = i >> 7, n = i & 127;
        Wd[i] = w1[q * (F_IN * F_IN) + n * (F_IN + 1)];   // weights1[i,j,n,n]
    }
    for (int i = tid; i < (F_IN * F_OUT) / 4; i += BLOCK) {
        ((float4*)W2s)[i] = ((const float4*)w2)[i];
    }
    __syncthreads();

    const int efill = lane >> 3;        // 0..7 : edge for the c-fill pass
    const int sub   = lane & 7;         // 0..7 : q-worker within edge
    const int k4    = (lane & 31) * 4;  // first n/k of this lane's float4 quad
    const int eh    = (lane >> 5) * 4;  // first edge of this lane's half (0 or 4)

    const int gw     = blockIdx.x * NWAVES + w;
    const int stride = gridDim.x * NWAVES;

    for (int g = gw; g < NGROUPS; g += stride) {
        const long base = (long)g * EPW;

        // ---- gather node attrs, build outer products c[e][q]
        int snd, rcv;
        if (is64) {
            snd = (int)p64[base + efill];
            rcv = (int)p64[N_EDGES + base + efill];
        } else {
            snd = p32[base + efill];
            rcv = p32[N_EDGES + base + efill];
        }
        const float* nas = na + snd * N_ELEM;
        const float* nar = na + rcv * N_ELEM;
        #pragma unroll
        for (int rep = 0; rep < 13; ++rep) {
            int q = rep * 8 + sub;
            if (q < NQ) {
                int i10 = (q * 205) >> 11;     // q / 10 for q<1024
                int j10 = q - i10 * 10;
                bw[efill * C_STRIDE + q] = nas[i10] * nar[j10];
            }
        }

        // prefetch edge feats (this lane's float4 of each of its 4 edges) -- in
        // flight (vmcnt) during all of phase A
        float4 ef0 = *(const float4*)&ef[(base + eh + 0) * F_IN + k4];
        float4 ef1 = *(const float4*)&ef[(base + eh + 1) * F_IN + k4];
        float4 ef2 = *(const float4*)&ef[(base + eh + 2) * F_IN + k4];
        float4 ef3 = *(const float4*)&ef[(base + eh + 3) * F_IN + k4];

        asm volatile("s_waitcnt lgkmcnt(0)" ::: "memory");  // c visible wave-wide

        // ---- phase A: t[e, k4..k4+3] = sum_q c[e,q] * Wd[q,n]
        // 8 LDS instr (4x Wd b128 lane-varying + 4x c b128 broadcast) per 64 FMA
        float4 a0 = {0,0,0,0}, a1 = {0,0,0,0}, a2 = {0,0,0,0}, a3 = {0,0,0,0};
        const float* cb = bw + eh * C_STRIDE;
        for (int q0 = 0; q0 < NQ; q0 += 4) {
            float4 wd0 = *(const float4*)&Wd[(q0 + 0) * F_IN + k4];
            float4 wd1 = *(const float4*)&Wd[(q0 + 1) * F_IN + k4];
            float4 wd2 = *(const float4*)&Wd[(q0 + 2) * F_IN + k4];
            float4 wd3 = *(const float4*)&Wd[(q0 + 3) * F_IN + k4];
            float4 c0 = *(const float4*)&cb[0 * C_STRIDE + q0];
            float4 c1 = *(const float4*)&cb[1 * C_STRIDE + q0];
            float4 c2 = *(const float4*)&cb[2 * C_STRIDE + q0];
            float4 c3 = *(const float4*)&cb[3 * C_STRIDE + q0];
            FMA4(a0, c0.x, wd0) FMA4(a0, c0.y, wd1) FMA4(a0, c0.z, wd2) FMA4(a0, c0.w, wd3)
            FMA4(a1, c1.x, wd0) FMA4(a1, c1.y, wd1) FMA4(a1, c1.z, wd2) FMA4(a1, c1.w, wd3)
            FMA4(a2, c2.x, wd0) FMA4(a2, c2.y, wd1) FMA4(a2, c2.z, wd2) FMA4(a2, c2.w, wd3)
            FMA4(a3, c3.x, wd0) FMA4(a3, c3.y, wd1) FMA4(a3, c3.z, wd2) FMA4(a3, c3.w, wd3)
        }

        // ---- modulate by edge feats, write M over the (now dead) c region.
        // DS ops are in-order per wave and all c reads were consumed by FMAs,
        // so the overwrite is safe without an extra wait.
        a0.x *= ef0.x; a0.y *= ef0.y; a0.z *= ef0.z; a0.w *= ef0.w;
        a1.x *= ef1.x; a1.y *= ef1.y; a1.z *= ef1.z; a1.w *= ef1.w;
        a2.x *= ef2.x; a2.y *= ef2.y; a2.z *= ef2.z; a2.w *= ef2.w;
        a3.x *= ef3.x; a3.y *= ef3.y; a3.z *= ef3.z; a3.w *= ef3.w;
        *(float4*)&bw[(eh + 0) * F_IN + k4] = a0;
        *(float4*)&bw[(eh + 1) * F_IN + k4] = a1;
        *(float4*)&bw[(eh + 2) * F_IN + k4] = a2;
        *(float4*)&bw[(eh + 3) * F_IN + k4] = a3;

        asm volatile("s_waitcnt lgkmcnt(0)" ::: "memory");  // M visible wave-wide

        // ---- phase B: out[e, k4..k4+3] = sum_n M[e,n] * W2[n,k]
        float4 o0 = {0,0,0,0}, o1 = {0,0,0,0}, o2 = {0,0,0,0}, o3 = {0,0,0,0};
        const float* mb = bw + eh * F_IN;
        for (int n0 = 0; n0 < F_IN; n0 += 4) {
            float4 u0 = *(const float4*)&W2s[(n0 + 0) * F_OUT + k4];
            float4 u1 = *(const float4*)&W2s[(n0 + 1) * F_OUT + k4];
            float4 u2 = *(const float4*)&W2s[(n0 + 2) * F_OUT + k4];
            float4 u3 = *(const float4*)&W2s[(n0 + 3) * F_OUT + k4];
            float4 m0 = *(const float4*)&mb[0 * F_IN + n0];
            float4 m1 = *(const float4*)&mb[1 * F_IN + n0];
            float4 m2 = *(const float4*)&mb[2 * F_IN + n0];
            float4 m3 = *(const float4*)&mb[3 * F_IN + n0];
            FMA4(o0, m0.x, u0) FMA4(o0, m0.y, u1) FMA4(o0, m0.z, u2) FMA4(o0, m0.w, u3)
            FMA4(o1, m1.x, u0) FMA4(o1, m1.y, u1) FMA4(o1, m1.z, u2) FMA4(o1, m1.w, u3)
            FMA4(o2, m2.x, u0) FMA4(o2, m2.y, u1) FMA4(o2, m2.z, u2) FMA4(o2, m2.w, u3)
            FMA4(o3, m3.x, u0) FMA4(o3, m3.y, u1) FMA4(o3, m3.z, u2) FMA4(o3, m3.w, u3)
        }

        *(float4*)&outp[(base + eh + 0) * F_OUT + k4] = o0;
        *(float4*)&outp[(base + eh + 1) * F_OUT + k4] = o1;
        *(float4*)&outp[(base + eh + 2) * F_OUT + k4] = o2;
        *(float4*)&outp[(base + eh + 3) * F_OUT + k4] = o3;
        // no trailing drain: next-iter c writes are DS-ordered after this
        // iteration's M reads (in-order per wave), and all reads were consumed.
    }
}

extern "C" void kernel_launch(void* const* d_in, const int* in_sizes, int n_in,
                              void* d_out, int out_size, void* d_ws, size_t ws_size,
                              hipStream_t stream) {
    const float* na   = (const float*)d_in[0];   // node_attrs  [50000,10]
    const float* ef   = (const float*)d_in[1];   // edge_feats  [800000,128]
    const void*  eidx = d_in[2];                 // edge_index  [2,800000] int32/int64
    const float* w1   = (const float*)d_in[3];   // weights1    [10,10,128,128]
    const float* w2   = (const float*)d_in[4];   // weights2    [128,128]
    float* outp = (float*)d_out;                 // [800000,128] fp32

    const size_t smem = SMEM_FLOATS * sizeof(float);   // 157696 B
    tpwb_kernel<<<dim3(256), dim3(BLOCK), smem, stream>>>(na, ef, eidx, w1, w2, outp);
}

// Round 2
// 1234.851 us; speedup vs baseline: 1.6705x; 1.0152x over previous
//
#include <hip/hip_runtime.h>

#define N_NODES 50000
#define N_EDGES 800000
#define N_ELEM  10
#define F_IN    128
#define F_OUT   128
#define NQ      100
#define EB      256                 // edges per block-iteration
#define NITER   (N_EDGES / EB)      // 3125 exactly
#define NWAVES  8
#define BLOCK   (NWAVES * 64)
#define CSTR    108                 // c row stride (432 B): eg-starts 12*eg mod 32 -> disjoint quads
#define MSTR    132                 // M row stride (528 B): eg-starts  4*eg mod 32 -> disjoint quads
#define SMEM_FLOATS (EB * MSTR)     // 33792 floats = 135168 B  (c[256][108] overlays M[256][132])

#define FMA4(acc, s, v)                      \
    acc.x = fmaf((s), (v).x, acc.x);         \
    acc.y = fmaf((s), (v).y, acc.y);         \
    acc.z = fmaf((s), (v).z, acc.z);         \
    acc.w = fmaf((s), (v).w, acc.w);

// densify diag(weights1): wd[q][n] = w1[q*16384 + n*129]
__global__ void wd_prep(const float* __restrict__ w1, float* __restrict__ wd) {
    int i = blockIdx.x * 256 + threadIdx.x;
    if (i < NQ * F_IN) {
        int q = i >> 7, n = i & 127;
        wd[i] = w1[q * (F_IN * F_IN) + n * (F_IN + 1)];
    }
}

template<bool DENSE>
__device__ __forceinline__ void load_wd8(float4 dst[4][2], const float* __restrict__ ws, int q, int col0) {
    #pragma unroll
    for (int i = 0; i < 4; ++i) {
        if constexpr (DENSE) {
            dst[i][0] = *(const float4*)&ws[(q + i) * F_IN + col0];
            dst[i][1] = *(const float4*)&ws[(q + i) * F_IN + col0 + 32];
        } else {
            #pragma unroll
            for (int h = 0; h < 2; ++h) {
                int n = col0 + h * 32;
                float4 r;
                r.x = ws[(q + i) * (F_IN * F_IN) + (n + 0) * (F_IN + 1)];
                r.y = ws[(q + i) * (F_IN * F_IN) + (n + 1) * (F_IN + 1)];
                r.z = ws[(q + i) * (F_IN * F_IN) + (n + 2) * (F_IN + 1)];
                r.w = ws[(q + i) * (F_IN * F_IN) + (n + 3) * (F_IN + 1)];
                dst[i][h] = r;
            }
        }
    }
}

__device__ __forceinline__ void load_w2_8(float4 dst[4][2], const float* __restrict__ w2, int n, int col0) {
    #pragma unroll
    for (int i = 0; i < 4; ++i) {
        dst[i][0] = *(const float4*)&w2[(n + i) * F_OUT + col0];
        dst[i][1] = *(const float4*)&w2[(n + i) * F_OUT + col0 + 32];
    }
}

__device__ __forceinline__ void load_cq(float4 cq[8], const float* crow0, int q0) {
    #pragma unroll
    for (int ee = 0; ee < 8; ++ee)
        cq[ee] = *(const float4*)&crow0[ee * 8 * CSTR + q0];
}

__device__ __forceinline__ void load_mq(float4 mq[8], const float* mrow0, int n0) {
    #pragma unroll
    for (int ee = 0; ee < 8; ++ee)
        mq[ee] = *(const float4*)&mrow0[ee * 8 * MSTR + n0];
}

__device__ __forceinline__ void fma_block(float4 acc[8][2], const float4 cq[8], const float4 wd[4][2]) {
    #pragma unroll
    for (int ee = 0; ee < 8; ++ee) {
        #pragma unroll
        for (int h = 0; h < 2; ++h) {
            FMA4(acc[ee][h], cq[ee].x, wd[0][h])
            FMA4(acc[ee][h], cq[ee].y, wd[1][h])
            FMA4(acc[ee][h], cq[ee].z, wd[2][h])
            FMA4(acc[ee][h], cq[ee].w, wd[3][h])
        }
    }
}

template<bool DENSE>
__global__ __launch_bounds__(BLOCK, 2)
void tpwb_kernel(const float* __restrict__ na,
                 const float* __restrict__ ef,
                 const void*  __restrict__ eidx,
                 const float* __restrict__ wdsrc,   // DENSE ? wd[100][128] : w1
                 const float* __restrict__ w2,
                 float* __restrict__ outp)
{
    extern __shared__ float smem[];      // c[EB][CSTR] overlaid by M[EB][MSTR]
    const int tid  = threadIdx.x;
    const int lane = tid & 63;
    const int w    = tid >> 6;

    // ---- detect edge_index dtype
    const int* p32 = (const int*)eidx;
    bool is64 = true;
    #pragma unroll
    for (int k = 1; k < 32; k += 2) { if (p32[k] != 0) is64 = false; }
    const long long* p64 = (const long long*)eidx;

    // wave tiling: 4 edge-panels x 2 col-panels of the 256x128 output
    const int ep    = w >> 1;            // 0..3
    const int cp    = w & 1;             // 0..1
    const int eg    = lane >> 3;         // 0..7 edge-group
    const int cg    = lane & 7;          // 0..7 col-group
    const int ebase = ep * 64;
    const int col0  = cp * 64 + cg * 4;  // quad h=0; h=1 at +32
    const float* crow0 = smem + (ebase + eg) * CSTR;
    const float* mrow0 = smem + (ebase + eg) * MSTR;

    for (int it = blockIdx.x; it < NITER; it += gridDim.x) {
        const long base = (long)it * EB;

        // ---- phase 0: cooperative c-fill (threads 0..255, one edge each)
        if (tid < EB) {
            int snd, rcv;
            if (is64) { snd = (int)p64[base + tid]; rcv = (int)p64[N_EDGES + base + tid]; }
            else      { snd = p32[base + tid];      rcv = p32[N_EDGES + base + tid]; }
            float as_[N_ELEM], ar_[N_ELEM];
            const float* nas = na + snd * N_ELEM;
            const float* nar = na + rcv * N_ELEM;
            #pragma unroll
            for (int i = 0; i < 5; ++i) {
                *(float2*)&as_[2 * i] = *(const float2*)&nas[2 * i];
                *(float2*)&ar_[2 * i] = *(const float2*)&nar[2 * i];
            }
            float* crow = smem + tid * CSTR;
            #pragma unroll
            for (int qq = 0; qq < 25; ++qq) {       // all indices compile-time -> registers
                const int q = qq * 4;
                float4 cc;
                cc.x = as_[(q + 0) / 10] * ar_[(q + 0) % 10];
                cc.y = as_[(q + 1) / 10] * ar_[(q + 1) % 10];
                cc.z = as_[(q + 2) / 10] * ar_[(q + 2) % 10];
                cc.w = as_[(q + 3) / 10] * ar_[(q + 3) % 10];
                *(float4*)&crow[q] = cc;
            }
        }
        __syncthreads();                            // c visible block-wide

        // ---- phase A: t[256x128] = c[256x100] x Wd[100x128]; Wd streamed from global
        float4 ta[8][2];
        #pragma unroll
        for (int ee = 0; ee < 8; ++ee) {
            ta[ee][0] = make_float4(0.f, 0.f, 0.f, 0.f);
            ta[ee][1] = make_float4(0.f, 0.f, 0.f, 0.f);
        }
        {
            float4 wa[4][2], wb[4][2], ca[8], cb[8];
            load_wd8<DENSE>(wa, wdsrc, 0, col0);
            load_cq(ca, crow0, 0);
            #pragma unroll 1
            for (int q0 = 0; q0 < 89; q0 += 8) {    // q0 = 0,8,...,88
                load_cq(cb, crow0, q0 + 4);
                load_wd8<DENSE>(wb, wdsrc, q0 + 4, col0);
                fma_block(ta, ca, wa);
                load_cq(ca, crow0, q0 + 8);
                load_wd8<DENSE>(wa, wdsrc, q0 + 8, col0);
                fma_block(ta, cb, wb);
            }
            fma_block(ta, ca, wa);                  // q0 = 96
        }
        __syncthreads();                            // all c reads done before M overlays

        // ---- modulate by edge feats, write M (overlays c region)
        {
            const long erow = base + ebase + eg;
            #pragma unroll
            for (int ee = 0; ee < 8; ++ee) {
                float4 e0 = *(const float4*)&ef[(erow + ee * 8) * F_IN + col0];
                float4 e1 = *(const float4*)&ef[(erow + ee * 8) * F_IN + col0 + 32];
                ta[ee][0].x *= e0.x; ta[ee][0].y *= e0.y; ta[ee][0].z *= e0.z; ta[ee][0].w *= e0.w;
                ta[ee][1].x *= e1.x; ta[ee][1].y *= e1.y; ta[ee][1].z *= e1.z; ta[ee][1].w *= e1.w;
                float* mrow = smem + (ebase + ee * 8 + eg) * MSTR;
                *(float4*)&mrow[col0]      = ta[ee][0];
                *(float4*)&mrow[col0 + 32] = ta[ee][1];
            }
        }
        __syncthreads();                            // M visible block-wide

        // ---- phase B: out[256x128] = M[256x128] x W2[128x128]; W2 streamed from global
        #pragma unroll
        for (int ee = 0; ee < 8; ++ee) {
            ta[ee][0] = make_float4(0.f, 0.f, 0.f, 0.f);
            ta[ee][1] = make_float4(0.f, 0.f, 0.f, 0.f);
        }
        {
            float4 wa[4][2], wb[4][2], ca[8], cb[8];
            load_w2_8(wa, w2, 0, col0);
            load_mq(ca, mrow0, 0);
            #pragma unroll 1
            for (int n0 = 0; n0 < 113; n0 += 8) {   // n0 = 0,8,...,112
                load_mq(cb, mrow0, n0 + 4);
                load_w2_8(wb, w2, n0 + 4, col0);
                fma_block(ta, ca, wa);
                load_mq(ca, mrow0, n0 + 8);
                load_w2_8(wa, w2, n0 + 8, col0);
                fma_block(ta, cb, wb);
            }
            load_mq(cb, mrow0, 124);
            load_w2_8(wb, w2, 124, col0);
            fma_block(ta, ca, wa);                  // n0 = 120
            fma_block(ta, cb, wb);                  // n0 = 124
        }

        // ---- store
        {
            const long erow = base + ebase + eg;
            #pragma unroll
            for (int ee = 0; ee < 8; ++ee) {
                *(float4*)&outp[(erow + ee * 8) * F_OUT + col0]      = ta[ee][0];
                *(float4*)&outp[(erow + ee * 8) * F_OUT + col0 + 32] = ta[ee][1];
            }
        }
        __syncthreads();                            // M reads done before next c-fill
    }
}

extern "C" void kernel_launch(void* const* d_in, const int* in_sizes, int n_in,
                              void* d_out, int out_size, void* d_ws, size_t ws_size,
                              hipStream_t stream) {
    const float* na   = (const float*)d_in[0];   // node_attrs  [50000,10]
    const float* ef   = (const float*)d_in[1];   // edge_feats  [800000,128]
    const void*  eidx = d_in[2];                 // edge_index  [2,800000] int32/int64
    const float* w1   = (const float*)d_in[3];   // weights1    [10,10,128,128]
    const float* w2   = (const float*)d_in[4];   // weights2    [128,128]
    float* outp = (float*)d_out;                 // [800000,128] fp32

    const size_t smem = SMEM_FLOATS * sizeof(float);   // 135168 B
    const bool dense = ws_size >= (size_t)(NQ * F_IN) * sizeof(float);
    if (dense) {
        wd_prep<<<dim3((NQ * F_IN + 255) / 256), dim3(256), 0, stream>>>(w1, (float*)d_ws);
        tpwb_kernel<true><<<dim3(256), dim3(BLOCK), smem, stream>>>(
            na, ef, eidx, (const float*)d_ws, w2, outp);
    } else {
        tpwb_kernel<false><<<dim3(256), dim3(BLOCK), smem, stream>>>(
            na, ef, eidx, w1, w2, outp);
    }
}